// Round 3
// baseline (475.257 us; speedup 1.0000x reference)
//
#include <hip/hip_runtime.h>

// GroupATTBLK: with F == FS == 160, AvgPool collapses F to F'=1, so the final
// softmax (over the singleton F' axis) is exactly 1.0 everywhere and the whole
// conv1/LN/PReLU/conv2 pipeline is dead code. out[b,c,t,f,0] = sum_d x[...,d],
// D=4 stride-1  =>  "sum each group of 4 consecutive floats".
//
// R2: same as R1 but using clang ext_vector_type for the nontemporal builtins
// (HIP's float4 is a class — the builtin rejects it). 64 B input / 16 B output
// per thread, nontemporal on both streams (335 MB input can't live in 32 MB
// aggregate L2 — don't pollute it; skip write-allocate on the output).

typedef float vfloat4 __attribute__((ext_vector_type(4)));

__global__ void __launch_bounds__(256)
sum_last4_x4(const vfloat4* __restrict__ x, vfloat4* __restrict__ out4, int n4) {
    int i = blockIdx.x * blockDim.x + threadIdx.x;
    if (i < n4) {
        const vfloat4* p = x + 4 * (size_t)i;     // 64 B contiguous per thread
        vfloat4 a = __builtin_nontemporal_load(p + 0);
        vfloat4 b = __builtin_nontemporal_load(p + 1);
        vfloat4 c = __builtin_nontemporal_load(p + 2);
        vfloat4 d = __builtin_nontemporal_load(p + 3);
        vfloat4 r;
        r.x = (a.x + a.y) + (a.z + a.w);
        r.y = (b.x + b.y) + (b.z + b.w);
        r.z = (c.x + c.y) + (c.z + c.w);
        r.w = (d.x + d.y) + (d.z + d.w);
        __builtin_nontemporal_store(r, out4 + i); // 16 B coalesced store
    }
}

extern "C" void kernel_launch(void* const* d_in, const int* in_sizes, int n_in,
                              void* d_out, int out_size, void* d_ws, size_t ws_size,
                              hipStream_t stream) {
    const vfloat4* x = (const vfloat4*)d_in[0];   // x: [B,C,T,F,4] fp32
    vfloat4* out4 = (vfloat4*)d_out;              // out: [B,C,T,F,1] fp32

    const int n4 = out_size / 4;                  // 20,971,520 / 4 = 5,242,880
    const int threads = 256;
    const int blocks = (n4 + threads - 1) / threads;
    sum_last4_x4<<<blocks, threads, 0, stream>>>(x, out4, n4);
}

// Round 4
// 451.168 us; speedup vs baseline: 1.0534x; 1.0534x over previous
//
#include <hip/hip_runtime.h>

// GroupATTBLK: with F == FS == 160, AvgPool collapses F to F'=1, so the final
// softmax (over the singleton F' axis) is exactly 1.0 everywhere and the whole
// conv1/LN/PReLU/conv2 pipeline is dead code with respect to the output:
//   out[b,c,t,f,0] = sum_d x[b,c,t,f,d],  D=4 stride-1.
//
// Traffic is provably minimal: 335.5 MB read (all of x contributes) + 83.9 MB
// write = 419 MB => ~65-75 us floor at the ~6.3 TB/s streaming ceiling.
// R1/R2 experiments (64 B/thread coarsening, nontemporal hints) were neutral
// to slightly negative — the simple form below is the best-measured config.
// Residual dur_us above the floor is harness reset traffic (1.34 GB ws
// poison + 335 MB input restore per timed iteration, visible in rocprof).

__global__ void __launch_bounds__(256)
sum_last4_kernel(const float4* __restrict__ x, float* __restrict__ out, int n) {
    int i = blockIdx.x * blockDim.x + threadIdx.x;
    if (i < n) {
        float4 v = x[i];                 // 16 B coalesced load: 1 KiB/wave
        out[i] = (v.x + v.y) + (v.z + v.w);  // 4 B coalesced store
    }
}

extern "C" void kernel_launch(void* const* d_in, const int* in_sizes, int n_in,
                              void* d_out, int out_size, void* d_ws, size_t ws_size,
                              hipStream_t stream) {
    const float4* x = (const float4*)d_in[0];   // x: [B,C,T,F,4] fp32
    float* out = (float*)d_out;                 // out: [B,C,T,F,1] fp32

    const int n = out_size;                     // 4*64*512*160 = 20,971,520
    const int threads = 256;
    const int blocks = (n + threads - 1) / threads;
    sum_last4_kernel<<<blocks, threads, 0, stream>>>(x, out, n);
}